// Round 3
// baseline (273.384 us; speedup 1.0000x reference)
//
#include <hip/hip_runtime.h>
#include <math.h>

// OrientationFilter: batched 2-state Kalman filter (theta, omega) with angle wrap.
// Inputs (setup_inputs order):
//   d_in[0] x0      [B,2,1] f32
//   d_in[1] P0      [B,2,2] f32
//   d_in[2] delta_t [B]     f32
//   d_in[3] Q       [B,2,2] f32 (diagonal)
//   d_in[4] z       [B,1,1] f32
//   d_in[5] R       [B,1,1] f32
// Output: x [B,2,1] then P [B,2,2], concatenated flat (6*B floats).
//
// R2: same as R1 (one thread per PAIR, no grid-stride loop, all loads up
// front) but nontemporal stores use clang ext_vector types — HIP's float4
// struct is rejected by __builtin_nontemporal_store.

#define TWO_PI_F 6.28318530717958647692f
#define INV_TWO_PI_F 0.15915494309189533577f

typedef float f32x4 __attribute__((ext_vector_type(4)));

__device__ __forceinline__ float wrap_to_pi(float a) {
    // a - 2*pi*round(a / 2*pi); rintf = round-to-nearest-even, matches jnp.round
    return fmaf(-TWO_PI_F, rintf(a * INV_TWO_PI_F), a);
}

__device__ __forceinline__ void kf_one(
    float th0, float om0, f32x4 p, float dt, float q0, float q3,
    float z, float R,
    float& xn0, float& xn1, f32x4& Pn)
{
    // ---- predict ----
    float theta = wrap_to_pi(fmaf(dt, om0, th0));
    float fp00 = fmaf(dt, p.z, p.x);   // p00 + dt*p10
    float fp01 = fmaf(dt, p.w, p.y);   // p01 + dt*p11
    float P00 = fmaf(dt, fp01, fp00) + q0;
    float P01 = fp01;
    float P10 = fmaf(dt, p.w, p.z);    // p10 + dt*p11
    float P11 = p.w + q3;

    // ---- update ----  H = [1,0]
    float S    = P00 + R;
    float invS = __frcp_rn(S);
    float K0   = P00 * invS;
    float K1   = P10 * invS;
    float innov = wrap_to_pi(z - theta);
    xn0 = wrap_to_pi(fmaf(K0, innov, theta));
    xn1 = fmaf(K1, innov, om0);
    float omK0 = 1.0f - K0;
    Pn.x = omK0 * P00;
    Pn.y = omK0 * P01;
    Pn.z = fmaf(-K1, P00, P10);
    Pn.w = fmaf(-K1, P01, P11);
}

__global__ void __launch_bounds__(256) orientation_filter_kernel(
    const float* __restrict__ x0,
    const float* __restrict__ P0,
    const float* __restrict__ dt_in,
    const float* __restrict__ Q,
    const float* __restrict__ z_in,
    const float* __restrict__ R_in,
    float* __restrict__ out_x,   // [B,2]
    float* __restrict__ out_P,   // [B,2,2]
    int B)
{
    int t = blockIdx.x * blockDim.x + threadIdx.x;  // pair index
    int b = 2 * t;
    if (b >= B) return;

    // ---- all loads up front, independent, 8-16B/lane coalesced ----
    f32x4 xx   = *reinterpret_cast<const f32x4*>(x0 + 2 * b);   // th0 om0 th1 om1
    f32x4 pA   = *reinterpret_cast<const f32x4*>(P0 + 4 * b);
    f32x4 pB   = *reinterpret_cast<const f32x4*>(P0 + 4 * b + 4);
    float2 dt2 = *reinterpret_cast<const float2*>(dt_in + b);
    f32x4 qA   = *reinterpret_cast<const f32x4*>(Q + 4 * b);
    f32x4 qB   = *reinterpret_cast<const f32x4*>(Q + 4 * b + 4);
    float2 z2  = *reinterpret_cast<const float2*>(z_in + b);
    float2 R2  = *reinterpret_cast<const float2*>(R_in + b);

    float xa0, xa1, xb0, xb1;
    f32x4 PnA, PnB;
    kf_one(xx.x, xx.y, pA, dt2.x, qA.x, qA.w, z2.x, R2.x, xa0, xa1, PnA);
    kf_one(xx.z, xx.w, pB, dt2.y, qB.x, qB.w, z2.y, R2.y, xb0, xb1, PnB);

    // ---- nontemporal vector stores ----
    f32x4 xv = {xa0, xa1, xb0, xb1};
    __builtin_nontemporal_store(xv,  reinterpret_cast<f32x4*>(out_x + 2 * b));
    __builtin_nontemporal_store(PnA, reinterpret_cast<f32x4*>(out_P + 4 * b));
    __builtin_nontemporal_store(PnB, reinterpret_cast<f32x4*>(out_P + 4 * b + 4));
}

extern "C" void kernel_launch(void* const* d_in, const int* in_sizes, int n_in,
                              void* d_out, int out_size, void* d_ws, size_t ws_size,
                              hipStream_t stream) {
    const float* x0 = (const float*)d_in[0];
    const float* P0 = (const float*)d_in[1];
    const float* dt = (const float*)d_in[2];
    const float* Q  = (const float*)d_in[3];
    const float* z  = (const float*)d_in[4];
    const float* R  = (const float*)d_in[5];

    int B = in_sizes[2];                  // delta_t is [B]
    float* out_x = (float*)d_out;         // first 2*B floats
    float* out_P = out_x + (size_t)2 * B; // next 4*B floats

    const int block = 256;
    int pairs = (B + 1) / 2;
    int grid = (pairs + block - 1) / block;

    orientation_filter_kernel<<<grid, block, 0, stream>>>(
        x0, P0, dt, Q, z, R, out_x, out_P, B);
}

// Round 4
// 256.194 us; speedup vs baseline: 1.0671x; 1.0671x over previous
//
#include <hip/hip_runtime.h>
#include <math.h>

// OrientationFilter: batched 2-state Kalman filter (theta, omega) with angle wrap.
// Inputs (setup_inputs order):
//   d_in[0] x0      [B,2,1] f32
//   d_in[1] P0      [B,2,2] f32
//   d_in[2] delta_t [B]     f32
//   d_in[3] Q       [B,2,2] f32 (diagonal)
//   d_in[4] z       [B,1,1] f32
//   d_in[5] R       [B,1,1] f32
// Output: x [B,2,1] then P [B,2,2], concatenated flat (6*B floats).
//
// R3: 4 batches/thread, ALL 13 vector loads issued before any compute,
// pinned by sched_barrier(0) so the compiler cannot cluster loads into
// small load->wait->consume groups (R2 evidence: VGPR_Count=16 meant only
// ~3 float4 loads in flight -> ~2.2 TB/s latency-bound). Plain stores
// (NT stores inflated WRITE_SIZE 96->133 MB in R2).

#define TWO_PI_F 6.28318530717958647692f
#define INV_TWO_PI_F 0.15915494309189533577f

typedef float f32x4 __attribute__((ext_vector_type(4)));

__device__ __forceinline__ float wrap_to_pi(float a) {
    // a - 2*pi*round(a / 2*pi); rintf = round-to-nearest-even, matches jnp.round
    return fmaf(-TWO_PI_F, rintf(a * INV_TWO_PI_F), a);
}

__device__ __forceinline__ void kf_one(
    float th0, float om0, f32x4 p, float dt, float q0, float q3,
    float z, float R,
    float& xn0, float& xn1, f32x4& Pn)
{
    // ---- predict ----
    float theta = wrap_to_pi(fmaf(dt, om0, th0));
    float fp00 = fmaf(dt, p.z, p.x);   // p00 + dt*p10
    float fp01 = fmaf(dt, p.w, p.y);   // p01 + dt*p11
    float P00 = fmaf(dt, fp01, fp00) + q0;
    float P01 = fp01;
    float P10 = fmaf(dt, p.w, p.z);    // p10 + dt*p11
    float P11 = p.w + q3;

    // ---- update ----  H = [1,0]
    float S    = P00 + R;
    float invS = __frcp_rn(S);
    float K0   = P00 * invS;
    float K1   = P10 * invS;
    float innov = wrap_to_pi(z - theta);
    xn0 = wrap_to_pi(fmaf(K0, innov, theta));
    xn1 = fmaf(K1, innov, om0);
    float omK0 = 1.0f - K0;
    Pn.x = omK0 * P00;
    Pn.y = omK0 * P01;
    Pn.z = fmaf(-K1, P00, P10);
    Pn.w = fmaf(-K1, P01, P11);
}

__global__ void __launch_bounds__(256, 1) orientation_filter_kernel(
    const float* __restrict__ x0,
    const float* __restrict__ P0,
    const float* __restrict__ dt_in,
    const float* __restrict__ Q,
    const float* __restrict__ z_in,
    const float* __restrict__ R_in,
    float* __restrict__ out_x,   // [B,2]
    float* __restrict__ out_P,   // [B,2,2]
    int B)
{
    int t = blockIdx.x * blockDim.x + threadIdx.x;  // quad index
    int b = 4 * t;
    if (b >= B) return;

    // ---- ALL loads issued before any compute (13 VMEM, 208 B/thread) ----
    const f32x4* x0v = reinterpret_cast<const f32x4*>(x0 + 2 * (size_t)b); // 2 vecs
    const f32x4* p0v = reinterpret_cast<const f32x4*>(P0 + 4 * (size_t)b); // 4 vecs
    const f32x4* qv  = reinterpret_cast<const f32x4*>(Q  + 4 * (size_t)b); // 4 vecs

    f32x4 xA = x0v[0];                 // th0 om0 th1 om1
    f32x4 xB = x0v[1];                 // th2 om2 th3 om3
    f32x4 pa = p0v[0], pb = p0v[1], pc = p0v[2], pd = p0v[3];
    f32x4 dtv = *reinterpret_cast<const f32x4*>(dt_in + b);
    f32x4 qa = qv[0], qb = qv[1], qc = qv[2], qd = qv[3];
    f32x4 zv = *reinterpret_cast<const f32x4*>(z_in + b);
    f32x4 Rv = *reinterpret_cast<const f32x4*>(R_in + b);

    // Nothing crosses this line: all 13 loads stay in flight together.
    __builtin_amdgcn_sched_barrier(0);

    float a0, a1, b0, b1, c0, c1, d0, d1;
    f32x4 PA, PB, PC, PD;
    kf_one(xA.x, xA.y, pa, dtv.x, qa.x, qa.w, zv.x, Rv.x, a0, a1, PA);
    kf_one(xA.z, xA.w, pb, dtv.y, qb.x, qb.w, zv.y, Rv.y, b0, b1, PB);
    kf_one(xB.x, xB.y, pc, dtv.z, qc.x, qc.w, zv.z, Rv.z, c0, c1, PC);
    kf_one(xB.z, xB.w, pd, dtv.w, qd.x, qd.w, zv.w, Rv.w, d0, d1, PD);

    // ---- stores (plain, vectorized) ----
    f32x4* oxv = reinterpret_cast<f32x4*>(out_x + 2 * (size_t)b);
    f32x4* opv = reinterpret_cast<f32x4*>(out_P + 4 * (size_t)b);
    f32x4 xv0 = {a0, a1, b0, b1};
    f32x4 xv1 = {c0, c1, d0, d1};
    oxv[0] = xv0;
    oxv[1] = xv1;
    opv[0] = PA;
    opv[1] = PB;
    opv[2] = PC;
    opv[3] = PD;
}

extern "C" void kernel_launch(void* const* d_in, const int* in_sizes, int n_in,
                              void* d_out, int out_size, void* d_ws, size_t ws_size,
                              hipStream_t stream) {
    const float* x0 = (const float*)d_in[0];
    const float* P0 = (const float*)d_in[1];
    const float* dt = (const float*)d_in[2];
    const float* Q  = (const float*)d_in[3];
    const float* z  = (const float*)d_in[4];
    const float* R  = (const float*)d_in[5];

    int B = in_sizes[2];                  // delta_t is [B]
    float* out_x = (float*)d_out;         // first 2*B floats
    float* out_P = out_x + (size_t)2 * B; // next 4*B floats

    const int block = 256;
    int quads = (B + 3) / 4;
    int grid = (quads + block - 1) / block;

    orientation_filter_kernel<<<grid, block, 0, stream>>>(
        x0, P0, dt, Q, z, R, out_x, out_P, B);
}

// Round 5
// 237.330 us; speedup vs baseline: 1.1519x; 1.0795x over previous
//
#include <hip/hip_runtime.h>
#include <math.h>

// OrientationFilter: batched 2-state Kalman filter (theta, omega) with angle wrap.
// Inputs (setup_inputs order):
//   d_in[0] x0      [B,2,1] f32
//   d_in[1] P0      [B,2,2] f32
//   d_in[2] delta_t [B]     f32
//   d_in[3] Q       [B,2,2] f32 (diagonal)
//   d_in[4] z       [B,1,1] f32
//   d_in[5] R       [B,1,1] f32
// Output: x [B,2,1] then P [B,2,2], concatenated flat (6*B floats).
//
// R5: isolate access-pattern contiguity. One batch per thread so EVERY
// load/store instruction is a contiguous wave-wide segment (R2/R3 made
// P0/Q lane-strided: 16B per lane at 32-64B stride = 2-4x cache lines per
// instruction). Exact grid, no grid-stride loop (R0's loop serialized
// iterations). Input streams are read-once -> nontemporal loads (skip L2
// allocation; leaves L2 to the 96MB store stream). Plain vector stores
// (NT stores inflated WRITE_SIZE 96->133MB in R2).

#define TWO_PI_F 6.28318530717958647692f
#define INV_TWO_PI_F 0.15915494309189533577f

typedef float f32x4 __attribute__((ext_vector_type(4)));
typedef float f32x2 __attribute__((ext_vector_type(2)));

__device__ __forceinline__ float wrap_to_pi(float a) {
    // a - 2*pi*round(a / 2*pi); rintf = round-to-nearest-even, matches jnp.round
    return fmaf(-TWO_PI_F, rintf(a * INV_TWO_PI_F), a);
}

__global__ void __launch_bounds__(256, 1) orientation_filter_kernel(
    const float* __restrict__ x0,
    const float* __restrict__ P0,
    const float* __restrict__ dt_in,
    const float* __restrict__ Q,
    const float* __restrict__ z_in,
    const float* __restrict__ R_in,
    float* __restrict__ out_x,   // [B,2]
    float* __restrict__ out_P,   // [B,2,2]
    int B)
{
    int b = blockIdx.x * blockDim.x + threadIdx.x;  // one batch per thread
    if (b >= B) return;

    // ---- all loads issued up front; every instruction wave-contiguous ----
    f32x2 x  = __builtin_nontemporal_load(reinterpret_cast<const f32x2*>(x0 + 2 * (size_t)b));
    f32x4 p  = __builtin_nontemporal_load(reinterpret_cast<const f32x4*>(P0 + 4 * (size_t)b));
    float dt = __builtin_nontemporal_load(dt_in + b);
    f32x4 q  = __builtin_nontemporal_load(reinterpret_cast<const f32x4*>(Q + 4 * (size_t)b));
    float z  = __builtin_nontemporal_load(z_in + b);
    float R  = __builtin_nontemporal_load(R_in + b);

    __builtin_amdgcn_sched_barrier(0);

    // ---- predict ----
    float theta = wrap_to_pi(fmaf(dt, x.y, x.x));
    float fp00 = fmaf(dt, p.z, p.x);   // p00 + dt*p10
    float fp01 = fmaf(dt, p.w, p.y);   // p01 + dt*p11
    float P00 = fmaf(dt, fp01, fp00) + q.x;
    float P01 = fp01;
    float P10 = fmaf(dt, p.w, p.z);    // p10 + dt*p11
    float P11 = p.w + q.w;

    // ---- update ----  H = [1,0]
    float S    = P00 + R;
    float invS = __frcp_rn(S);
    float K0   = P00 * invS;
    float K1   = P10 * invS;
    float innov = wrap_to_pi(z - theta);
    float xn0 = wrap_to_pi(fmaf(K0, innov, theta));
    float xn1 = fmaf(K1, innov, x.y);
    float omK0 = 1.0f - K0;
    f32x4 Pn;
    Pn.x = omK0 * P00;
    Pn.y = omK0 * P01;
    Pn.z = fmaf(-K1, P00, P10);
    Pn.w = fmaf(-K1, P01, P11);

    // ---- stores (plain, wave-contiguous) ----
    f32x2 xv = {xn0, xn1};
    *reinterpret_cast<f32x2*>(out_x + 2 * (size_t)b) = xv;
    *reinterpret_cast<f32x4*>(out_P + 4 * (size_t)b) = Pn;
}

extern "C" void kernel_launch(void* const* d_in, const int* in_sizes, int n_in,
                              void* d_out, int out_size, void* d_ws, size_t ws_size,
                              hipStream_t stream) {
    const float* x0 = (const float*)d_in[0];
    const float* P0 = (const float*)d_in[1];
    const float* dt = (const float*)d_in[2];
    const float* Q  = (const float*)d_in[3];
    const float* z  = (const float*)d_in[4];
    const float* R  = (const float*)d_in[5];

    int B = in_sizes[2];                  // delta_t is [B]
    float* out_x = (float*)d_out;         // first 2*B floats
    float* out_P = out_x + (size_t)2 * B; // next 4*B floats

    const int block = 256;
    int grid = (B + block - 1) / block;   // exact grid, one shot

    orientation_filter_kernel<<<grid, block, 0, stream>>>(
        x0, P0, dt, Q, z, R, out_x, out_P, B);
}